// Round 10
// baseline (142.619 us; speedup 1.0000x reference)
//
#include <hip/hip_runtime.h>

// GCNConv forward, round 10: identical to round 9 except agg_gemm_k's
// __launch_bounds__ relaxed (512,6)->(512,4): VGPR budget 85->128 so the
// 8-deep uint4 gather burst stays in flight (round 9 allocated only 36 VGPRs
// and serialized the burst). Occupancy unchanged (VGPR<=128 still 16 waves/CU).
//
//  1. memset gcnt/ovfc/ovf_w
//  2. sortA_k: blocks [0,SAB): 4096 edges/block; LDS 391-bucket histogram
//     (col>>7) + LDS staging sorted by bucket (bkid recorded per slot);
//     per-block reserve-atomics on XCD-replicated counters; coalesced runs
//     into stage[(b,xcc)]. blocks [SAB,SAB+XB4): x->bf16. rest: W->W^T bf16.
//  3. sortB_k: per bucket (128 nodes): ONE sweep (edges in registers, rank
//     from LDS atomic) -> scan -> dinv + CSR (offA,cntA) -> eout scatter.
//  4. agg_gemm_k (512 thr, 32 nodes/block):
//     phase A: 4 nodes/wave, 16 lanes x uint4 row gathers, 8 in flight,
//              folded overflow replay; y (bf16) -> LDS.
//     barrier; phase B: 8 waves x 2 (16x16) MFMA tiles over k=128; float4
//              epilogue via per-wave LDS scratch; + bias.

#define F 128
#define MAXOVF 4096
#define SHIFT 7
#define RNG 128           // nodes per coarse bucket
#define NBMAX 512
#define SA_BS 1024
#define SA_EPB 4096

typedef __attribute__((ext_vector_type(8))) short bf16x8;
typedef __attribute__((ext_vector_type(4))) float f32x4;

__device__ __forceinline__ unsigned bf16rne(float f) {
    unsigned u = __float_as_uint(f);
    return (u + 0x7fffu + ((u >> 16) & 1u)) >> 16;
}
__device__ __forceinline__ float bflo(unsigned u) { return __uint_as_float(u << 16); }
__device__ __forceinline__ float bfhi(unsigned u) { return __uint_as_float(u & 0xffff0000u); }

// ---- 2. pass A: coarse counting sort + fused conversions ----
__global__ __launch_bounds__(1024) void sortA_k(
        const int* __restrict__ row, const int* __restrict__ col,
        const float* __restrict__ ew, const float* __restrict__ x,
        const float* __restrict__ W,
        unsigned* __restrict__ gcnt,              // [8][NBMAX] reserve counters
        unsigned long long* __restrict__ stage,   // [(b*8+xcc)*capb + j]
        unsigned* __restrict__ ovf_w, int* __restrict__ ovf, int* __restrict__ ovfc,
        uint4* __restrict__ xb4, unsigned short* __restrict__ Wt,
        int E, int NB, int capb, int SAB, int XB4, long ng8) {
    int tid = threadIdx.x;
    int blk = blockIdx.x;
    if (blk >= SAB) {                             // fused conversion blocks
        if (blk < SAB + XB4) {
            long i = (long)(blk - SAB) * 1024 + tid;
            if (i < ng8) {
                const float4* x4 = (const float4*)x;
                float4 a = x4[2 * i], c = x4[2 * i + 1];
                uint4 o;
                o.x = bf16rne(a.x) | (bf16rne(a.y) << 16);
                o.y = bf16rne(a.z) | (bf16rne(a.w) << 16);
                o.z = bf16rne(c.x) | (bf16rne(c.y) << 16);
                o.w = bf16rne(c.z) | (bf16rne(c.w) << 16);
                xb4[i] = o;
            }
        } else {
            int idx = (blk - SAB - XB4) * 1024 + tid;
            if (idx < F * F) {
                int k = idx >> 7, nn = idx & 127;
                Wt[nn * F + k] = (unsigned short)bf16rne(W[idx]);
            }
        }
        return;
    }
    __shared__ unsigned hist[NBMAX], sc[NBMAX], rbase[NBMAX], ravail[NBMAX];
    __shared__ unsigned long long stg[SA_EPB];
    __shared__ unsigned short bkid[SA_EPB];
    unsigned xcc;
    asm volatile("s_getreg_b32 %0, hwreg(HW_REG_XCC_ID, 0, 4)" : "=s"(xcc));
    xcc &= 7u;
    long e0 = (long)blk * SA_EPB;
    for (int i = tid; i < NBMAX; i += SA_BS) hist[i] = 0;
    __syncthreads();
    unsigned long long pk[4];
    int bk[4]; unsigned rk[4];
    #pragma unroll
    for (int k = 0; k < 4; ++k) {
        long e = e0 + k * SA_BS + tid;
        bk[k] = -1;
        if (e < E) {
            int c = col[e], r = row[e];
            float w = ew[e];
            unsigned wq = __float2uint_rn(w * 32768.0f);
            if (wq > 32767u) wq = 32767u;
            pk[k] = ((unsigned long long)(unsigned)c << 32) |
                    ((unsigned long long)(unsigned)r << 15) | wq;
            bk[k] = c >> SHIFT;
            rk[k] = atomicAdd(&hist[bk[k]], 1u);      // LDS atomic
        }
    }
    __syncthreads();
    if (tid < NBMAX) sc[tid] = hist[tid];
    __syncthreads();
    for (int d = 1; d < NBMAX; d <<= 1) {             // inclusive scan
        unsigned v = 0;
        if (tid < NBMAX && tid >= d) v = sc[tid - d];
        __syncthreads();
        if (tid < NBMAX) sc[tid] += v;
        __syncthreads();
    }
    if (tid < NB) {                                   // reserve global space
        unsigned cnt = hist[tid], bs = 0, av = 0;
        if (cnt > 0) {
            bs = atomicAdd(&gcnt[xcc * NBMAX + tid], cnt);
            av = (bs < (unsigned)capb) ? ((unsigned)capb - bs) : 0u;
        }
        rbase[tid] = bs;
        ravail[tid] = av;
    }
    __syncthreads();
    #pragma unroll
    for (int k = 0; k < 4; ++k)                       // stage bucket-sorted
        if (bk[k] >= 0) {
            unsigned slot = sc[bk[k]] - hist[bk[k]] + rk[k];
            stg[slot] = pk[k];
            bkid[slot] = (unsigned short)bk[k];
        }
    __syncthreads();
    int tot = (int)sc[NBMAX - 1];
    for (int i = tid; i < tot; i += SA_BS) {          // coalesced run copy-out
        int lo = (int)bkid[i];
        unsigned j = (unsigned)i - (sc[lo] - hist[lo]);
        unsigned long long v = stg[i];
        if (j < ravail[lo]) {
            stage[((size_t)lo * 8 + xcc) * capb + rbase[lo] + j] = v;
        } else {                                      // rare exact fallback
            int c = (int)(v >> 32);
            int r = (int)((v >> 15) & 0x1FFFFu);
            unsigned wq = (unsigned)(v & 0x7FFFu);
            atomicAdd(&ovf_w[c], wq);                 // keep deg exact
            int p = atomicAdd(ovfc, 1);
            if (p < MAXOVF) {
                ovf[3 * p] = r; ovf[3 * p + 1] = c; ovf[3 * p + 2] = (int)wq;
            }
        }
    }
}

// ---- 3. pass B: single-sweep per-bucket CSR + dinv (edges in registers) ----
__global__ __launch_bounds__(1024) void sortB_k(
        const unsigned long long* __restrict__ stage,
        const unsigned* __restrict__ gcnt, const unsigned* __restrict__ ovf_w,
        unsigned* __restrict__ eout, int* __restrict__ offA, int* __restrict__ cntA,
        float* __restrict__ dinv, int n, int capb) {
    __shared__ unsigned cnt[RNG], wsum[RNG], scn[RNG], bex[RNG];
    __shared__ unsigned rpre[9];
    int tid = threadIdx.x;
    int b = blockIdx.x;
    int node0 = b << SHIFT;
    int nodes = n - node0; if (nodes > RNG) nodes = RNG; if (nodes < 0) nodes = 0;
    if (tid < RNG) { cnt[tid] = 0; wsum[tid] = 0; }
    if (tid == 0) {                                   // region prefix (8 regions)
        unsigned acc = 0; rpre[0] = 0;
        #pragma unroll
        for (int xr = 0; xr < 8; ++xr) {
            unsigned m = gcnt[xr * NBMAX + b]; if (m > (unsigned)capb) m = capb;
            acc += m; rpre[xr + 1] = acc;
        }
    }
    __syncthreads();
    int T = (int)rpre[8];                             // total edges in bucket
    unsigned ent[8]; unsigned short noa[8], rka[8];   // capb<=1024 -> <=8/thread
    int myc = 0;
    for (int i = tid; i < T; i += 1024) {             // ONE sweep
        int xr = 0;
        while (rpre[xr + 1] <= (unsigned)i) ++xr;
        unsigned j = (unsigned)i - rpre[xr];
        unsigned long long v = stage[((size_t)b * 8 + xr) * capb + j];
        int no = (int)(v >> 32) - node0;
        unsigned wq = (unsigned)(v & 0x7FFFu);
        unsigned rk = atomicAdd(&cnt[no], 1u);        // rank within node
        atomicAdd(&wsum[no], wq);
        ent[myc] = (unsigned)((((v >> 15) & 0x1FFFFu) << 15) | wq);
        noa[myc] = (unsigned short)no; rka[myc] = (unsigned short)rk;
        ++myc;
    }
    __syncthreads();
    if (tid < RNG) scn[tid] = cnt[tid];
    __syncthreads();
    for (int d = 1; d < RNG; d <<= 1) {               // inclusive scan over 128
        unsigned v = 0;
        if (tid < RNG && tid >= d) v = scn[tid - d];
        __syncthreads();
        if (tid < RNG) scn[tid] += v;
        __syncthreads();
    }
    if (tid < RNG) bex[tid] = scn[tid] - cnt[tid];    // exclusive base
    __syncthreads();
    if (tid < nodes) {
        int node = node0 + tid;
        float deg = (float)(wsum[tid] + ovf_w[node]) * (1.0f / 32768.0f) + 1.0f;
        dinv[node] = rsqrtf(deg);
        offA[node] = b * (capb * 8) + (int)bex[tid];
        cntA[node] = (int)cnt[tid];
    }
    unsigned base = (unsigned)(b * (capb * 8));
    for (int k = 0; k < myc; ++k)                     // scatter from registers
        eout[base + bex[noa[k]] + rka[k]] = ent[k];
}

// ---- 4. fused aggregate (full occupancy) + MFMA GEMM ----
__global__ __launch_bounds__(512, 4) void agg_gemm_k(
        const uint4* __restrict__ xb4, const float* __restrict__ dinv,
        const int* __restrict__ offA, const int* __restrict__ cntA,
        const unsigned* __restrict__ eout,
        const int* __restrict__ ovf, const int* __restrict__ ovfc,
        const unsigned short* __restrict__ Wt, const float* __restrict__ bias,
        float* __restrict__ out, int n) {
    __shared__ unsigned ys[32 * 68];       // y tile (bf16 pairs), row stride 68
    __shared__ float epi[8][2 * 320];      // per-wave C scratch: 2 tiles, stride 20
    int wv = threadIdx.x >> 6, lane = threadIdx.x & 63;

    // ---- phase A: aggregate 4 nodes per wave ----
    {
        int g = lane >> 4, l = lane & 15;  // node-quarter, col-lane (8 cols)
        int nl = wv * 4 + g;               // local node 0..31
        int i = blockIdx.x * 32 + nl;
        if (i < n) {
            float di = dinv[i];
            uint4 xs = xb4[(size_t)i * 16 + l];
            float a0 = di * bflo(xs.x), a1 = di * bfhi(xs.x);
            float a2 = di * bflo(xs.y), a3 = di * bfhi(xs.y);
            float a4 = di * bflo(xs.z), a5 = di * bfhi(xs.z);
            float a6 = di * bflo(xs.w), a7 = di * bfhi(xs.w);
            int cnt = cntA[i], off = offA[i];
            for (int bb = 0; bb < cnt; bb += 32) {    // 32 edges / metadata pass
                int e0 = bb + 2 * l;
                unsigned m0 = (e0     < cnt) ? eout[off + e0]     : 0u;
                unsigned m1 = (e0 + 1 < cnt) ? eout[off + e0 + 1] : 0u;
                int sv0 = (int)(m0 >> 15), sv1 = (int)(m1 >> 15);
                float wk0 = (float)(m0 & 0x7FFFu) * (1.0f / 32768.0f) * dinv[sv0];
                float wk1 = (float)(m1 & 0x7FFFu) * (1.0f / 32768.0f) * dinv[sv1];
                int cb = cnt - bb; if (cb > 32) cb = 32;
                for (int j0 = 0; j0 < cb; j0 += 8) {  // 8 gathers in flight
                    int base = g * 16 + (j0 >> 1);    // tail lanes carry wk=0
                    int   s0 = __shfl(sv0, base),     s1 = __shfl(sv1, base);
                    int   s2 = __shfl(sv0, base + 1), s3 = __shfl(sv1, base + 1);
                    int   s4 = __shfl(sv0, base + 2), s5 = __shfl(sv1, base + 2);
                    int   s6 = __shfl(sv0, base + 3), s7 = __shfl(sv1, base + 3);
                    float w0 = __shfl(wk0, base),     w1 = __shfl(wk1, base);
                    float w2 = __shfl(wk0, base + 1), w3 = __shfl(wk1, base + 1);
                    float w4 = __shfl(wk0, base + 2), w5 = __shfl(wk1, base + 2);
                    float w6 = __shfl(wk0, base + 3), w7 = __shfl(wk1, base + 3);
                    uint4 u0 = xb4[(size_t)s0 * 16 + l];
                    uint4 u1 = xb4[(size_t)s1 * 16 + l];
                    uint4 u2 = xb4[(size_t)s2 * 16 + l];
                    uint4 u3 = xb4[(size_t)s3 * 16 + l];
                    uint4 u4 = xb4[(size_t)s4 * 16 + l];
                    uint4 u5 = xb4[(size_t)s5 * 16 + l];
                    uint4 u6 = xb4[(size_t)s6 * 16 + l];
                    uint4 u7 = xb4[(size_t)s7 * 16 + l];
                    a0 += w0 * bflo(u0.x) + w1 * bflo(u1.x) + w2 * bflo(u2.x) + w3 * bflo(u3.x)
                        + w4 * bflo(u4.x) + w5 * bflo(u5.x) + w6 * bflo(u6.x) + w7 * bflo(u7.x);
                    a1 += w0 * bfhi(u0.x) + w1 * bfhi(u1.x) + w2 * bfhi(u2.x) + w3 * bfhi(u3.x)
                        + w4 * bfhi(u4.x) + w5 * bfhi(u5.x) + w6 * bfhi(u6.x) + w7 * bfhi(u7.x);
                    a2 += w0 * bflo(u0.y) + w1 * bflo(u1.y) + w2 * bflo(u2.y) + w3 * bflo(u3.y)
                        + w4 * bflo(u4.y) + w5 * bflo(u5.y) + w6 * bflo(u6.y) + w7 * bflo(u7.y);
                    a3 += w0 * bfhi(u0.y) + w1 * bfhi(u1.y) + w2 * bfhi(u2.y) + w3 * bfhi(u3.y)
                        + w4 * bfhi(u4.y) + w5 * bfhi(u5.y) + w6 * bfhi(u6.y) + w7 * bfhi(u7.y);
                    a4 += w0 * bflo(u0.z) + w1 * bflo(u1.z) + w2 * bflo(u2.z) + w3 * bflo(u3.z)
                        + w4 * bflo(u4.z) + w5 * bflo(u5.z) + w6 * bflo(u6.z) + w7 * bflo(u7.z);
                    a5 += w0 * bfhi(u0.z) + w1 * bfhi(u1.z) + w2 * bfhi(u2.z) + w3 * bfhi(u3.z)
                        + w4 * bfhi(u4.z) + w5 * bfhi(u5.z) + w6 * bfhi(u6.z) + w7 * bfhi(u7.z);
                    a6 += w0 * bflo(u0.w) + w1 * bflo(u1.w) + w2 * bflo(u2.w) + w3 * bflo(u3.w)
                        + w4 * bflo(u4.w) + w5 * bflo(u5.w) + w6 * bflo(u6.w) + w7 * bflo(u7.w);
                    a7 += w0 * bfhi(u0.w) + w1 * bfhi(u1.w) + w2 * bfhi(u2.w) + w3 * bfhi(u3.w)
                        + w4 * bfhi(u4.w) + w5 * bfhi(u5.w) + w6 * bfhi(u6.w) + w7 * bfhi(u7.w);
                }
            }
            int oc = *ovfc;                           // folded overflow replay
            if (oc > 0) {                             // (normally oc == 0)
                if (oc > MAXOVF) oc = MAXOVF;
                for (int k = 0; k < oc; ++k) {
                    if (ovf[3 * k + 1] == i) {
                        int sv = ovf[3 * k];
                        float wk = (float)ovf[3 * k + 2] * (1.0f / 32768.0f) * dinv[sv];
                        uint4 u = xb4[(size_t)sv * 16 + l];
                        a0 += wk * bflo(u.x); a1 += wk * bfhi(u.x);
                        a2 += wk * bflo(u.y); a3 += wk * bfhi(u.y);
                        a4 += wk * bflo(u.z); a5 += wk * bfhi(u.z);
                        a6 += wk * bflo(u.w); a7 += wk * bfhi(u.w);
                    }
                }
            }
            a0 *= di; a1 *= di; a2 *= di; a3 *= di;
            a4 *= di; a5 *= di; a6 *= di; a7 *= di;
            uint4 o;
            o.x = bf16rne(a0) | (bf16rne(a1) << 16);
            o.y = bf16rne(a2) | (bf16rne(a3) << 16);
            o.z = bf16rne(a4) | (bf16rne(a5) << 16);
            o.w = bf16rne(a6) | (bf16rne(a7) << 16);
            *(uint4*)&ys[nl * 68 + l * 4] = o;        // 272B row stride, 16B aligned
        }
    }
    __syncthreads();

    // ---- phase B: 32x128 GEMM from LDS; wave -> (row-tile, 2 col-tiles) ----
    {
        int m = lane & 15, q = lane >> 4;
        int rt = wv & 1;                   // row-tile 0..1
        int ct0 = wv >> 1;                 // col-tiles ct0, ct0+4
        int gr0 = blockIdx.x * 32 + rt * 16;
        f32x4 acc0 = (f32x4){0.f, 0.f, 0.f, 0.f};
        f32x4 acc1 = (f32x4){0.f, 0.f, 0.f, 0.f};
        #pragma unroll
        for (int kk = 0; kk < 4; ++kk) {
            bf16x8 a = *(const bf16x8*)&ys[(rt * 16 + m) * 68 + kk * 16 + q * 4];
            bf16x8 b0 = *(const bf16x8*)(Wt + (size_t)(ct0 * 16 + m) * F + kk * 32 + q * 8);
            bf16x8 b1 = *(const bf16x8*)(Wt + (size_t)((ct0 + 4) * 16 + m) * F + kk * 32 + q * 8);
            acc0 = __builtin_amdgcn_mfma_f32_16x16x32_bf16(a, b0, acc0, 0, 0, 0);
            acc1 = __builtin_amdgcn_mfma_f32_16x16x32_bf16(a, b1, acc1, 0, 0, 0);
        }
        // epilogue via per-wave LDS scratch (within-wave dep, no barrier)
        float* ep = epi[wv];
        #pragma unroll
        for (int v = 0; v < 4; ++v) {
            ep[(q * 4 + v) * 20 + m]       = acc0[v];
            ep[320 + (q * 4 + v) * 20 + m] = acc1[v];
        }
        int r = lane >> 2, c4 = lane & 3;  // 16 rows x 4 col-groups
        #pragma unroll
        for (int tt = 0; tt < 2; ++tt) {
            int ct = ct0 + tt * 4;
            float4 bv = ((const float4*)bias)[ct * 4 + c4];
            float4 v4 = *(float4*)&ep[tt * 320 + r * 20 + c4 * 4];
            v4.x += bv.x; v4.y += bv.y; v4.z += bv.z; v4.w += bv.w;
            int rr = gr0 + r;
            if (rr < n) ((float4*)out)[(size_t)rr * 32 + ct * 4 + c4] = v4;
        }
    }
}

// ---- launcher ----
extern "C" void kernel_launch(void* const* d_in, const int* in_sizes, int n_in,
                              void* d_out, int out_size, void* d_ws, size_t ws_size,
                              hipStream_t stream) {
    const float* x  = (const float*)d_in[0];
    const int*   ei = (const int*)d_in[1];
    const float* ew = (const float*)d_in[2];
    const float* W  = (const float*)d_in[3];
    const float* b  = (const float*)d_in[4];
    float* out = (float*)d_out;

    int n = in_sizes[0] / F;          // 50000
    int E = in_sizes[2];              // 800000
    const int* row = ei;              // sources
    const int* col = ei + E;          // targets
    int NB = (n + RNG - 1) >> SHIFT;  // 391 coarse buckets

    // workspace layout, u32 units, 256B-aligned regions
    float* ws = (float*)d_ws;
    size_t o = 0;
    auto take = [&](size_t elems) { size_t r = o; o += (elems + 63) & ~63ull; return r; };
    size_t o_gcnt  = take(8 * NBMAX);
    size_t o_ovfc  = take(64);
    size_t o_ovfw  = take(n);
    size_t zero_end = o;                               // memset [0, zero_end)
    size_t o_ovf   = take((size_t)MAXOVF * 3);
    size_t o_dinv  = take(n);
    size_t o_offA  = take(n);
    size_t o_cntA  = take(n);
    size_t o_wt    = take(F * F / 2);
    size_t o_xb    = take((size_t)n * (F / 2));
    // adaptive sub-region capacity: stage (u64 = 2 units) + eout (1 unit)
    size_t units = ws_size / 4;
    size_t remain = (units > o + 128) ? (units - o - 128) : 0;
    int capb = (int)(remain / ((size_t)NB * 8 * 3));
    if (capb > 1024) capb = 1024;     // <=1024 guarantees <=8 entries/thread in sortB
    if (capb < 256)  capb = 256;      // ws too small: best effort
    size_t o_stage = take((size_t)NB * 8 * capb * 2);
    size_t o_eout  = take((size_t)NB * 8 * capb);
    (void)n_in; (void)out_size; (void)o_eout;

    unsigned* gcnt = (unsigned*)(ws + o_gcnt);
    int*      ovfc = (int*)(ws + o_ovfc);
    unsigned* ovfw = (unsigned*)(ws + o_ovfw);
    int*      ovf  = (int*)(ws + o_ovf);
    float*    dinv = ws + o_dinv;
    int*      offA = (int*)(ws + o_offA);
    int*      cntA = (int*)(ws + o_cntA);
    unsigned short* Wt = (unsigned short*)(ws + o_wt);
    unsigned* xb   = (unsigned*)(ws + o_xb);
    unsigned long long* stage = (unsigned long long*)(ws + o_stage);
    unsigned* eout = (unsigned*)(ws + o_eout);

    hipMemsetAsync(d_ws, 0, zero_end * sizeof(float), stream);

    int SAB = (E + SA_EPB - 1) / SA_EPB;               // 196
    long ng8 = (long)n * (F / 8);                      // uint4 groups in x
    int XB4 = (int)((ng8 + 1023) / 1024);
    int WB = (F * F + 1023) / 1024;

    sortA_k<<<SAB + XB4 + WB, SA_BS, 0, stream>>>(row, col, ew, x, W, gcnt, stage,
                                                  ovfw, ovf, ovfc, (uint4*)xb, Wt,
                                                  E, NB, capb, SAB, XB4, ng8);
    sortB_k<<<NB, SA_BS, 0, stream>>>(stage, gcnt, ovfw, eout, offA, cntA,
                                      dinv, n, capb);
    agg_gemm_k<<<(n + 31) / 32, 512, 0, stream>>>((const uint4*)xb, dinv, offA,
                                                  cntA, eout, ovf, ovfc, Wt, b,
                                                  out, n);
}